// Round 5
// baseline (843.462 us; speedup 1.0000x reference)
//
#include <hip/hip_runtime.h>
#include <hip/hip_bf16.h>

#define NTOK 8192
#define DM 1024
#define DFF 4096
#define NE 8
#define TPAD 72  // max 256-row tiles: 16384/256 + 8 partials, padded

typedef __attribute__((ext_vector_type(8))) short bf16x8;
typedef __attribute__((ext_vector_type(4))) float f32x4;

__device__ __forceinline__ ushort f2bf(float f) {
  __hip_bfloat16 h = __float2bfloat16(f);
  return *reinterpret_cast<ushort*>(&h);
}

// ---------- W [R][C] fp32 -> Wt [C][R] bf16, per expert (blockIdx.z) ----------
__global__ void transpose_cvt(const float* __restrict__ in, ushort* __restrict__ out,
                              int R, int C) {
  __shared__ float t[64][65];
  const float* inp = in + (size_t)blockIdx.z * R * C;
  ushort* op = out + (size_t)blockIdx.z * R * C;
  int c0 = blockIdx.x * 64, r0 = blockIdx.y * 64;
  int tid = threadIdx.x;
#pragma unroll
  for (int it = 0; it < 4; ++it) {
    int r = it * 16 + (tid >> 4);
    int c = (tid & 15) * 4;
    float4 v = *reinterpret_cast<const float4*>(inp + (size_t)(r0 + r) * C + c0 + c);
    t[r][c] = v.x; t[r][c + 1] = v.y; t[r][c + 2] = v.z; t[r][c + 3] = v.w;
  }
  __syncthreads();
  int c = tid >> 2, rc = (tid & 3) * 16;
  union { ushort us[16]; uint4 q[2]; } u;
#pragma unroll
  for (int i = 0; i < 16; ++i) u.us[i] = f2bf(t[rc + i][c]);
  uint4* dst = reinterpret_cast<uint4*>(op + (size_t)(c0 + c) * R + r0 + rc);
  dst[0] = u.q[0];
  dst[1] = u.q[1];
}

// ---------------- router (fused x->bf16 conversion) ----------------
__global__ void router_kernel(const float* __restrict__ x, const float* __restrict__ router,
                              int* __restrict__ cnt, int* __restrict__ list,
                              float* __restrict__ wa, ushort* __restrict__ xb) {
  __shared__ float rl[DM * NE];  // 32 KB
  int tid = threadIdx.x;
  for (int i = tid; i < DM * NE / 4; i += 256)
    reinterpret_cast<float4*>(rl)[i] = reinterpret_cast<const float4*>(router)[i];
  __syncthreads();
  int wave = tid >> 6, lane = tid & 63;
  int tok0 = blockIdx.x * 32 + wave * 8;
  for (int tI = 0; tI < 8; ++tI) {
    int tok = tok0 + tI;
    float acc[NE];
#pragma unroll
    for (int e2 = 0; e2 < NE; ++e2) acc[e2] = 0.f;
    const float4* xr = reinterpret_cast<const float4*>(x + (size_t)tok * DM);
    ushort xo[16];
#pragma unroll
    for (int c = 0; c < 4; ++c) {
      float4 v = xr[lane * 4 + c];
      int d = lane * 16 + c * 4;
      const float* vv = reinterpret_cast<const float*>(&v);
#pragma unroll
      for (int q = 0; q < 4; ++q) {
        float xv = vv[q];
        xo[c * 4 + q] = f2bf(xv);
#pragma unroll
        for (int e2 = 0; e2 < NE; ++e2) acc[e2] += xv * rl[(d + q) * NE + e2];
      }
    }
    // write bf16 row (fused cvt): lane covers cols lane*16..+15
    *reinterpret_cast<uint4*>(xb + (size_t)tok * DM + lane * 16) =
        *reinterpret_cast<const uint4*>(&xo[0]);
    *reinterpret_cast<uint4*>(xb + (size_t)tok * DM + lane * 16 + 8) =
        *reinterpret_cast<const uint4*>(&xo[8]);
    for (int off = 32; off > 0; off >>= 1) {
#pragma unroll
      for (int e2 = 0; e2 < NE; ++e2) acc[e2] += __shfl_xor(acc[e2], off, 64);
    }
    if (lane == 0) {
      int i0 = 0; float v0 = acc[0];
#pragma unroll
      for (int e2 = 1; e2 < NE; ++e2) { if (acc[e2] > v0) { v0 = acc[e2]; i0 = e2; } }
      int i1 = -1; float v1 = -3.4e38f;
#pragma unroll
      for (int e2 = 0; e2 < NE; ++e2) { if (e2 != i0 && acc[e2] > v1) { v1 = acc[e2]; i1 = e2; } }
      float e1 = expf(v1 - v0);
      float w0 = 1.f / (1.f + e1);
      float w1 = e1 / (1.f + e1);
      int s0 = atomicAdd(&cnt[i0], 1);
      list[i0 * NTOK + s0] = tok * 2;
      wa[tok * 2] = w0;
      int s1 = atomicAdd(&cnt[i1], 1);
      list[i1 * NTOK + s1] = tok * 2 + 1;
      wa[tok * 2 + 1] = w1;
    }
  }
}

// ---------------- tile table: flat tile -> (expert, tTile), BM=256 ----------------
__global__ void build_tiles(const int* __restrict__ cnt, unsigned* __restrict__ table) {
  if (threadIdx.x == 0) {
    int t = 0;
    for (int e = 0; e < NE; ++e) {
      int nt = (cnt[e] + 255) >> 8;
      for (int i = 0; i < nt; ++i) table[t++] = ((unsigned)e << 16) | (unsigned)i;
    }
    for (; t < TPAD; ++t) table[t] = 0xFFFFFFFFu;
  }
}

// ---------------- helpers ----------------
__device__ __forceinline__ void gl_lds16(unsigned long long g, void* s) {
  __builtin_amdgcn_global_load_lds(
      (const __attribute__((address_space(1))) unsigned int*)g,
      (__attribute__((address_space(3))) unsigned int*)s, 16, 0, 0);
}

#define WAITV0() asm volatile("s_waitcnt vmcnt(0)" ::: "memory")

__device__ __forceinline__ void BARRIER() {
  asm volatile("" ::: "memory");
  __builtin_amdgcn_s_barrier();
  asm volatile("" ::: "memory");
}

// ---------------- sparse expert GEMM: 256x256, 8 waves, XCD-banded grid ----------------
// BK=64 (128B XOR-swizzled rows, verified zero-conflict), 2-slot double buffer,
// body [STAGE(t+1); COMPUTE(t); vmcnt(0); barrier] — stage latency hides under
// 64 MFMA + 24 ds_read_b128 per wave per step. 1-D grid: xcd = bid&7 owns a
// contiguous (column-chunk x tile) band, tile-fastest => concurrent blocks on an
// XCD share 2-4 B-panels (~2MB, L2-resident).
template <int PASS>
__launch_bounds__(512, 2)
__global__ void moe_gemm(const ushort* __restrict__ Abase,
                         const ushort* __restrict__ Wt,
                         const int* __restrict__ cnt,
                         const int* __restrict__ list,
                         const unsigned* __restrict__ table,
                         const float* __restrict__ wa,
                         ushort* __restrict__ Hbuf,
                         float* __restrict__ out) {
  constexpr int K_FULL = (PASS == 1) ? DM : DFF;
  constexpr int KSPLIT = (PASS == 1) ? 1 : 2;
  constexpr int KCH = K_FULL / KSPLIT;   // 1024 / 2048
  constexpr int NK = KCH / 64;           // 16 / 32
  constexpr int NNv = (PASS == 1) ? 16 : 4;  // BN=256 column tiles
  constexpr int CPX = (NNv * KSPLIT) / 8;    // column-chunks per XCD: 2 / 1
  constexpr int NB = (PASS == 1) ? DFF : DM;
  constexpr int SLOT = 256 * 128;  // 32 KB per operand slot

  const int bid = blockIdx.x;
  const int k8 = bid & 7;        // XCD (dispatch round-robin assumption; perf-only)
  const int j = bid >> 3;
  const int ci = j / TPAD;       // 0..CPX-1
  const int tt = j % TPAD;
  unsigned td = table[tt];
  if (td == 0xFFFFFFFFu) return;  // uniform exit before any barrier
  const int e = td >> 16;
  const int tTile = td & 0xFFFF;
  const int n = cnt[e];
  const int cc = k8 * CPX + ci;
  const int nTile = cc % NNv;
  const int kc = cc / NNv;
  const int kbase = kc * KCH;

  __shared__ __attribute__((aligned(16))) char As[2 * SLOT];
  __shared__ __attribute__((aligned(16))) char Bs[2 * SLOT];
  __shared__ int aL[256];
  __shared__ unsigned long long pL[256];

  const int tid = threadIdx.x;
  if (tid < 256) {
    int slot = tTile * 256 + tid;
    int sl = (slot < n) ? slot : (n - 1);
    int a = list[e * NTOK + sl];
    aL[tid] = (slot < n) ? a : -1;
    size_t row = (PASS == 1) ? (size_t)(a >> 1) : (size_t)a;
    pL[tid] = (unsigned long long)Abase + (row * K_FULL + kbase) * 2;  // byte addr
  }
  __syncthreads();

  // staging: 8 threads/row x 16B, 4 row-groups of 64 per operand.
  // swizzle folded into SOURCE column; LDS dest linear (rule 21).
  const char* WtE = (const char*)(Wt + (size_t)e * NB * K_FULL);
  const int sr = tid >> 3;        // 0..63
  const int sc = (tid & 7) * 16;  // base byte col
  unsigned long long sA[4], sB[4];
  unsigned dst[4];
#pragma unroll
  for (int jj = 0; jj < 4; ++jj) {
    int row = jj * 64 + sr;
    unsigned swc = (unsigned)(sc ^ ((row & 7) << 4));
    sA[jj] = pL[row] + swc;
    sB[jj] = (unsigned long long)WtE + ((size_t)(nTile * 256 + row) * K_FULL + kbase) * 2 + swc;
    dst[jj] = (unsigned)(row * 128 + sc);
  }

  auto STAGE = [&](int s) {
#pragma unroll
    for (int jj = 0; jj < 4; ++jj) {
      gl_lds16(sA[jj], As + s * SLOT + dst[jj]);
      gl_lds16(sB[jj], Bs + s * SLOT + dst[jj]);
      sA[jj] += 128;
      sB[jj] += 128;
    }
  };

  const int wv = tid >> 6, lane = tid & 63;
  const int wm = wv >> 2, wn = wv & 3;   // 2M x 4N waves
  const int r0 = wm * 128, c0 = wn * 64;

  f32x4 acc[8][4];
#pragma unroll
  for (int m = 0; m < 8; ++m)
#pragma unroll
    for (int nn = 0; nn < 4; ++nn) acc[m][nn] = (f32x4){0.f, 0.f, 0.f, 0.f};

  auto COMPUTE = [&](int s) {
    const char* a_ = As + s * SLOT;
    const char* b_ = Bs + s * SLOT;
#pragma unroll
    for (int kk = 0; kk < 2; ++kk) {
      const int kb = kk * 64 + (lane >> 4) * 16;
      bf16x8 bfr[4];
#pragma unroll
      for (int nn = 0; nn < 4; ++nn) {
        int row = c0 + nn * 16 + (lane & 15);
        bfr[nn] = *reinterpret_cast<const bf16x8*>(b_ + row * 128 + (kb ^ ((row & 7) << 4)));
      }
      __builtin_amdgcn_s_setprio(1);
#pragma unroll
      for (int m = 0; m < 8; ++m) {
        int row = r0 + m * 16 + (lane & 15);
        bf16x8 af = *reinterpret_cast<const bf16x8*>(a_ + row * 128 + (kb ^ ((row & 7) << 4)));
#pragma unroll
        for (int nn = 0; nn < 4; ++nn)
          acc[m][nn] = __builtin_amdgcn_mfma_f32_16x16x32_bf16(af, bfr[nn], acc[m][nn], 0, 0, 0);
      }
      __builtin_amdgcn_s_setprio(0);
    }
  };

  // prologue: fill slot 0, drain, barrier
  STAGE(0);
  WAITV0();
  BARRIER();
  // steady state: issue next stage, compute current, drain, barrier
  for (int kt = 0; kt < NK; ++kt) {
    int cur = kt & 1;
    if (kt + 1 < NK) STAGE(cur ^ 1);
    COMPUTE(cur);
    WAITV0();   // next-stage loads had the whole compute block to land
    BARRIER();
  }

  // epilogue — C/D layout: col = lane&15, row = (lane>>4)*4 + j
#pragma unroll
  for (int m = 0; m < 8; ++m) {
#pragma unroll
    for (int jr = 0; jr < 4; ++jr) {
      int lr = r0 + m * 16 + (lane >> 4) * 4 + jr;
      int a = aL[lr];
      if (a < 0) continue;
      if (PASS == 1) {
        ushort* hrow = Hbuf + (size_t)a * DFF + nTile * 256 + c0 + (lane & 15);
#pragma unroll
        for (int nn = 0; nn < 4; ++nn) {
          float v = acc[m][nn][jr];
          hrow[nn * 16] = f2bf(v / (1.f + expf(-v)));  // swish
        }
      } else {
        float w = wa[a];
        int tok = a >> 1;
        float* orow = out + (size_t)tok * DM + nTile * 256 + c0 + (lane & 15);
#pragma unroll
        for (int nn = 0; nn < 4; ++nn)
          atomicAdd(&orow[nn * 16], w * acc[m][nn][jr]);  // 2 experts x KSPLIT contributions
      }
    }
  }
}

extern "C" void kernel_launch(void* const* d_in, const int* in_sizes, int n_in,
                              void* d_out, int out_size, void* d_ws, size_t ws_size,
                              hipStream_t stream) {
  const float* x = (const float*)d_in[0];
  const float* router = (const float*)d_in[1];
  const float* W1 = (const float*)d_in[2];
  const float* W2 = (const float*)d_in[3];
  float* out = (float*)d_out;
  char* ws = (char*)d_ws;

  size_t off = 0;
  ushort* Xb = (ushort*)(ws + off); off += (size_t)NTOK * DM * 2;          // 16 MB
  ushort* Wt1 = (ushort*)(ws + off); off += (size_t)NE * DM * DFF * 2;     // 64 MB
  ushort* Wt2 = (ushort*)(ws + off); off += (size_t)NE * DM * DFF * 2;     // 64 MB
  ushort* H   = (ushort*)(ws + off); off += (size_t)NTOK * 2 * DFF * 2;    // 128 MB
  int* cnt  = (int*)(ws + off); off += 256;
  int* list = (int*)(ws + off); off += (size_t)NE * NTOK * 4;
  float* wa = (float*)(ws + off); off += (size_t)NTOK * 2 * 4;
  unsigned* table = (unsigned*)(ws + off); off += TPAD * 4;

  hipMemsetAsync(out, 0, (size_t)NTOK * DM * sizeof(float), stream);
  hipMemsetAsync(cnt, 0, NE * sizeof(int), stream);

  transpose_cvt<<<dim3(DFF / 64, DM / 64, NE), 256, 0, stream>>>(W1, Wt1, DM, DFF);
  transpose_cvt<<<dim3(DM / 64, DFF / 64, NE), 256, 0, stream>>>(W2, Wt2, DFF, DM);
  router_kernel<<<NTOK / 32, 256, 0, stream>>>(x, router, cnt, list, wa, Xb);
  build_tiles<<<1, 64, 0, stream>>>(cnt, table);

  // pass1: 16 nTiles x KSPLIT1 -> 2 column-chunks/XCD; grid = 8*2*TPAD
  moe_gemm<1><<<8 * 2 * TPAD, 512, 0, stream>>>(Xb, Wt1, cnt, list, table, wa, H, out);
  // pass2: 4 nTiles x KSPLIT2 -> 1 column-chunk/XCD; grid = 8*1*TPAD
  moe_gemm<2><<<8 * 1 * TPAD, 512, 0, stream>>>(H, Wt2, cnt, list, table, wa, H, out);
}

// Round 6
// 760.245 us; speedup vs baseline: 1.1095x; 1.1095x over previous
//
#include <hip/hip_runtime.h>
#include <hip/hip_bf16.h>

#define NTOK 8192
#define DM 1024
#define DFF 4096
#define NE 8
#define MAXT 136  // max 128-row tiles: 16384/128 + 8 partials

typedef __attribute__((ext_vector_type(8))) short bf16x8;
typedef __attribute__((ext_vector_type(4))) float f32x4;

__device__ __forceinline__ ushort f2bf(float f) {
  __hip_bfloat16 h = __float2bfloat16(f);
  return *reinterpret_cast<ushort*>(&h);
}

// ---------- W [R][C] fp32 -> Wt [C][R] bf16, per expert (blockIdx.z) ----------
__global__ void transpose_cvt(const float* __restrict__ in, ushort* __restrict__ out,
                              int R, int C) {
  __shared__ float t[64][65];
  const float* inp = in + (size_t)blockIdx.z * R * C;
  ushort* op = out + (size_t)blockIdx.z * R * C;
  int c0 = blockIdx.x * 64, r0 = blockIdx.y * 64;
  int tid = threadIdx.x;
#pragma unroll
  for (int it = 0; it < 4; ++it) {
    int r = it * 16 + (tid >> 4);
    int c = (tid & 15) * 4;
    float4 v = *reinterpret_cast<const float4*>(inp + (size_t)(r0 + r) * C + c0 + c);
    t[r][c] = v.x; t[r][c + 1] = v.y; t[r][c + 2] = v.z; t[r][c + 3] = v.w;
  }
  __syncthreads();
  int c = tid >> 2, rc = (tid & 3) * 16;
  union { ushort us[16]; uint4 q[2]; } u;
#pragma unroll
  for (int i = 0; i < 16; ++i) u.us[i] = f2bf(t[rc + i][c]);
  uint4* dst = reinterpret_cast<uint4*>(op + (size_t)(c0 + c) * R + r0 + rc);
  dst[0] = u.q[0];
  dst[1] = u.q[1];
}

// ---------------- router (fused x->bf16 conversion) ----------------
__global__ void router_kernel(const float* __restrict__ x, const float* __restrict__ router,
                              int* __restrict__ cnt, int* __restrict__ list,
                              float* __restrict__ wa, ushort* __restrict__ xb) {
  __shared__ float rl[DM * NE];  // 32 KB
  int tid = threadIdx.x;
  for (int i = tid; i < DM * NE / 4; i += 256)
    reinterpret_cast<float4*>(rl)[i] = reinterpret_cast<const float4*>(router)[i];
  __syncthreads();
  int wave = tid >> 6, lane = tid & 63;
  int tok0 = blockIdx.x * 32 + wave * 8;
  for (int tI = 0; tI < 8; ++tI) {
    int tok = tok0 + tI;
    float acc[NE];
#pragma unroll
    for (int e2 = 0; e2 < NE; ++e2) acc[e2] = 0.f;
    const float4* xr = reinterpret_cast<const float4*>(x + (size_t)tok * DM);
    ushort xo[16];
#pragma unroll
    for (int c = 0; c < 4; ++c) {
      float4 v = xr[lane * 4 + c];
      int d = lane * 16 + c * 4;
      const float* vv = reinterpret_cast<const float*>(&v);
#pragma unroll
      for (int q = 0; q < 4; ++q) {
        float xv = vv[q];
        xo[c * 4 + q] = f2bf(xv);
#pragma unroll
        for (int e2 = 0; e2 < NE; ++e2) acc[e2] += xv * rl[(d + q) * NE + e2];
      }
    }
    *reinterpret_cast<uint4*>(xb + (size_t)tok * DM + lane * 16) =
        *reinterpret_cast<const uint4*>(&xo[0]);
    *reinterpret_cast<uint4*>(xb + (size_t)tok * DM + lane * 16 + 8) =
        *reinterpret_cast<const uint4*>(&xo[8]);
    for (int off = 32; off > 0; off >>= 1) {
#pragma unroll
      for (int e2 = 0; e2 < NE; ++e2) acc[e2] += __shfl_xor(acc[e2], off, 64);
    }
    if (lane == 0) {
      int i0 = 0; float v0 = acc[0];
#pragma unroll
      for (int e2 = 1; e2 < NE; ++e2) { if (acc[e2] > v0) { v0 = acc[e2]; i0 = e2; } }
      int i1 = -1; float v1 = -3.4e38f;
#pragma unroll
      for (int e2 = 0; e2 < NE; ++e2) { if (e2 != i0 && acc[e2] > v1) { v1 = acc[e2]; i1 = e2; } }
      float e1 = expf(v1 - v0);
      float w0 = 1.f / (1.f + e1);
      float w1 = e1 / (1.f + e1);
      int s0 = atomicAdd(&cnt[i0], 1);
      list[i0 * NTOK + s0] = tok * 2;
      wa[tok * 2] = w0;
      int s1 = atomicAdd(&cnt[i1], 1);
      list[i1 * NTOK + s1] = tok * 2 + 1;
      wa[tok * 2 + 1] = w1;
    }
  }
}

// ---------------- tile table: flat tile -> (expert, tTile), BM=128 ----------------
__global__ void build_tiles(const int* __restrict__ cnt, unsigned* __restrict__ table) {
  if (threadIdx.x == 0) {
    int t = 0;
    for (int e = 0; e < NE; ++e) {
      int nt = (cnt[e] + 127) >> 7;
      for (int i = 0; i < nt; ++i) table[t++] = ((unsigned)e << 16) | (unsigned)i;
    }
    for (; t < MAXT; ++t) table[t] = 0xFFFFFFFFu;
  }
}

// ---------------- helpers ----------------
__device__ __forceinline__ void gl_lds16(unsigned long long g, void* s) {
  __builtin_amdgcn_global_load_lds(
      (const __attribute__((address_space(1))) unsigned int*)g,
      (__attribute__((address_space(3))) unsigned int*)s, 16, 0, 0);
}

#define WAITV0() asm volatile("s_waitcnt vmcnt(0)" ::: "memory")

__device__ __forceinline__ void BARRIER() {
  asm volatile("" ::: "memory");
  __builtin_amdgcn_s_barrier();
  asm volatile("" ::: "memory");
}

// ---------------- sparse expert GEMM: occupancy-first single-buffer ----------------
// 128x128 tile, BK=64 (128B XOR-swizzled rows, verified zero-conflict), 4 waves,
// SINGLE-buffered LDS (34 KB) -> 4 blocks/CU; cross-block wave overlap (m114) is
// the latency-hiding mechanism, not intra-block pipelining. Per-block K-rotation
// desynchronizes co-resident blocks' stage/compute phases (anti-convoy).
// XCD-banded 1-D grid: xcd=bid&7 owns CPX column chunks, tile-fastest => resident
// blocks on an XCD share A-tiles and ~2 B-panels (L2-resident; R5-verified FETCH cut).
template <int PASS, int CPX>
__launch_bounds__(256, 4)
__global__ void moe_gemm(const ushort* __restrict__ Abase,
                         const ushort* __restrict__ Wt,
                         const int* __restrict__ cnt,
                         const int* __restrict__ list,
                         const unsigned* __restrict__ table,
                         const float* __restrict__ wa,
                         ushort* __restrict__ Hbuf,
                         float* __restrict__ out) {
  constexpr int K = (PASS == 1) ? DM : DFF;
  constexpr int NK = K / 64;
  constexpr int NB = (PASS == 1) ? DFF : DM;

  const int bid = blockIdx.x;
  const int xcd = bid & 7;
  const int j = bid >> 3;
  const int c = j / MAXT;
  const int t = j - c * MAXT;
  unsigned td = table[t];
  if (td == 0xFFFFFFFFu) return;  // uniform exit before any barrier
  const int e = td >> 16;
  const int tTile = td & 0xFFFF;
  const int n = cnt[e];
  const int nTile = xcd * CPX + c;

  __shared__ __attribute__((aligned(16))) char As[128 * 128];  // 16 KB
  __shared__ __attribute__((aligned(16))) char Bs[128 * 128];  // 16 KB
  __shared__ int aL[128];
  __shared__ unsigned long long pL[128];

  const int tid = threadIdx.x;
  if (tid < 128) {
    int slot = tTile * 128 + tid;
    int sl = (slot < n) ? slot : (n - 1);
    int a = list[e * NTOK + sl];
    aL[tid] = (slot < n) ? a : -1;
    size_t row = (PASS == 1) ? (size_t)(a >> 1) : (size_t)a;
    pL[tid] = (unsigned long long)(Abase + row * K);  // byte address of A row
  }
  __syncthreads();

  // staging: 8 threads/row x 16B, 4 row-groups of 32 per operand.
  // swizzle folded into SOURCE column; LDS dest linear (rule 21).
  const char* WtE = (const char*)(Wt + (size_t)e * NB * K);
  const int sr = tid >> 3;        // 0..31
  const int sc = (tid & 7) * 16;  // base byte col
  unsigned long long sA0[4], sB0[4];
  unsigned dst[4];
#pragma unroll
  for (int jj = 0; jj < 4; ++jj) {
    int row = jj * 32 + sr;
    unsigned swc = (unsigned)(sc ^ ((row & 7) << 4));
    sA0[jj] = pL[row] + swc;
    sB0[jj] = (unsigned long long)WtE + (size_t)(nTile * 128 + row) * (K * 2) + swc;
    dst[jj] = (unsigned)(row * 128 + sc);
  }

  const int wv = tid >> 6, lane = tid & 63;
  const int r0 = (wv >> 1) * 64, c0 = (wv & 1) * 64;

  f32x4 acc[4][4];
#pragma unroll
  for (int m = 0; m < 4; ++m)
#pragma unroll
    for (int nn = 0; nn < 4; ++nn) acc[m][nn] = (f32x4){0.f, 0.f, 0.f, 0.f};

  // per-block K-rotation: co-resident blocks start at different K slices
  const int rot = bid & (NK - 1);

  for (int kt = 0; kt < NK; ++kt) {
    int slice = kt + rot;
    if (slice >= NK) slice -= NK;
    const unsigned kbyt = (unsigned)slice << 7;  // slice*128 bytes
    // STAGE into the single slot
#pragma unroll
    for (int jj = 0; jj < 4; ++jj) {
      gl_lds16(sA0[jj] + kbyt, As + dst[jj]);
      gl_lds16(sB0[jj] + kbyt, Bs + dst[jj]);
    }
    WAITV0();
    BARRIER();
    // COMPUTE
#pragma unroll
    for (int kk = 0; kk < 2; ++kk) {
      const int kb = kk * 64 + (lane >> 4) * 16;
      bf16x8 af[4], bfr[4];
#pragma unroll
      for (int m = 0; m < 4; ++m) {
        int row = r0 + m * 16 + (lane & 15);
        af[m] = *reinterpret_cast<const bf16x8*>(As + row * 128 + (kb ^ ((row & 7) << 4)));
      }
#pragma unroll
      for (int nn = 0; nn < 4; ++nn) {
        int row = c0 + nn * 16 + (lane & 15);
        bfr[nn] = *reinterpret_cast<const bf16x8*>(Bs + row * 128 + (kb ^ ((row & 7) << 4)));
      }
      __builtin_amdgcn_s_setprio(1);
#pragma unroll
      for (int m = 0; m < 4; ++m)
#pragma unroll
        for (int nn = 0; nn < 4; ++nn)
          acc[m][nn] = __builtin_amdgcn_mfma_f32_16x16x32_bf16(af[m], bfr[nn], acc[m][nn], 0, 0, 0);
      __builtin_amdgcn_s_setprio(0);
    }
    BARRIER();  // WAR: all waves done reading before next stage overwrites
  }

  // epilogue — C/D layout: col = lane&15, row = (lane>>4)*4 + j
#pragma unroll
  for (int m = 0; m < 4; ++m) {
#pragma unroll
    for (int jr = 0; jr < 4; ++jr) {
      int lr = r0 + m * 16 + (lane >> 4) * 4 + jr;
      int a = aL[lr];
      if (a < 0) continue;
      if (PASS == 1) {
        ushort* hrow = Hbuf + (size_t)a * DFF + nTile * 128 + c0 + (lane & 15);
#pragma unroll
        for (int nn = 0; nn < 4; ++nn) {
          float v = acc[m][nn][jr];
          hrow[nn * 16] = f2bf(v / (1.f + expf(-v)));  // swish
        }
      } else {
        float w = wa[a];
        int tok = a >> 1;
        float* orow = out + (size_t)tok * DM + nTile * 128 + c0 + (lane & 15);
#pragma unroll
        for (int nn = 0; nn < 4; ++nn)
          atomicAdd(&orow[nn * 16], w * acc[m][nn][jr]);  // exactly 2 contributions
      }
    }
  }
}

extern "C" void kernel_launch(void* const* d_in, const int* in_sizes, int n_in,
                              void* d_out, int out_size, void* d_ws, size_t ws_size,
                              hipStream_t stream) {
  const float* x = (const float*)d_in[0];
  const float* router = (const float*)d_in[1];
  const float* W1 = (const float*)d_in[2];
  const float* W2 = (const float*)d_in[3];
  float* out = (float*)d_out;
  char* ws = (char*)d_ws;

  size_t off = 0;
  ushort* Xb = (ushort*)(ws + off); off += (size_t)NTOK * DM * 2;          // 16 MB
  ushort* Wt1 = (ushort*)(ws + off); off += (size_t)NE * DM * DFF * 2;     // 64 MB
  ushort* Wt2 = (ushort*)(ws + off); off += (size_t)NE * DM * DFF * 2;     // 64 MB
  ushort* H   = (ushort*)(ws + off); off += (size_t)NTOK * 2 * DFF * 2;    // 128 MB
  int* cnt  = (int*)(ws + off); off += 256;
  int* list = (int*)(ws + off); off += (size_t)NE * NTOK * 4;
  float* wa = (float*)(ws + off); off += (size_t)NTOK * 2 * 4;
  unsigned* table = (unsigned*)(ws + off); off += MAXT * 4;

  hipMemsetAsync(out, 0, (size_t)NTOK * DM * sizeof(float), stream);
  hipMemsetAsync(cnt, 0, NE * sizeof(int), stream);

  transpose_cvt<<<dim3(DFF / 64, DM / 64, NE), 256, 0, stream>>>(W1, Wt1, DM, DFF);
  transpose_cvt<<<dim3(DM / 64, DFF / 64, NE), 256, 0, stream>>>(W2, Wt2, DFF, DM);
  router_kernel<<<NTOK / 32, 256, 0, stream>>>(x, router, cnt, list, wa, Xb);
  build_tiles<<<1, 64, 0, stream>>>(cnt, table);

  // pass1: 32 nTiles -> 4 chunks/XCD; pass2: 8 nTiles -> 1 chunk/XCD (full K per block)
  moe_gemm<1, 4><<<8 * 4 * MAXT, 256, 0, stream>>>(Xb, Wt1, cnt, list, table, wa, H, out);
  moe_gemm<2, 1><<<8 * 1 * MAXT, 256, 0, stream>>>(H, Wt2, cnt, list, table, wa, H, out);
}